// Round 18
// baseline (204.717 us; speedup 1.0000x reference)
//
#include <hip/hip_runtime.h>
#include <hip/hip_bf16.h>

// GPT-2 attention block, MI355X. B=1 T=4096 C=1024 H=16 D=64.
// R17: GEMMs rebuilt as 128x256 / BK=64 / 8-wave / 2-slot counted-vmcnt ring
//      (96KB LDS, 1 block/CU). Per-step wall ~1000cyc >> 500cyc load latency =>
//      ring covers latency within the block (R13 failed at 154cyc x depth3).
//      vmcnt(6)/step (6 stage ops/wave), stage t+2 post-bar2 into freed slot,
//      clamped tail dummies, drain only at end. LDS layout + shared-k perm =
//      R13's correctness-verified scheme; per-wave frag/epilogue = R12's (64x64).
//      Flash (R16 3-slot ring, 63.7us), prep, combine: verbatim.

typedef unsigned short u16;
typedef u16 u16x4 __attribute__((ext_vector_type(4)));
typedef u16 u16x8 __attribute__((ext_vector_type(8)));
typedef __bf16 bf16x8 __attribute__((ext_vector_type(8)));
typedef float f32x4 __attribute__((ext_vector_type(4)));

#define T_SEQ 4096
#define C_DIM 1024
#define NH 16
#define HD 64
#define QSC 0.18033688f  // 0.125 * log2(e): folded into Q at QKV epilogue
#define NJOBS 1152       // 16 heads x 72 chunk-jobs (256q rows, <=8 kv-tiles each)

static __device__ __forceinline__ u16 f2bf(float f) {
    __hip_bfloat16 h = __float2bfloat16(f);
    return __builtin_bit_cast(u16, h);
}

static __device__ __forceinline__ float bf2f(u16 u) {
    return __builtin_bit_cast(float, (unsigned)u << 16);
}

static __device__ __forceinline__ bf16x8 ldfr(const u16* base, int byteoff) {
    return __builtin_bit_cast(bf16x8, *(const u16x8*)(base + (byteoff >> 1)));
}

static __device__ __forceinline__ bf16x8 ldc(const u16* p) {
    return __builtin_bit_cast(bf16x8, *(const u16x8*)p);
}

static __device__ __forceinline__ void gld_lds16(const void* g, void* l) {
    __builtin_amdgcn_global_load_lds((const __attribute__((address_space(1))) void*)g,
                                     (__attribute__((address_space(3))) void*)l, 16, 0, 0);
}

#define MFMA16(a, b, c) __builtin_amdgcn_mfma_f32_16x16x32_bf16((a), (b), (c), 0, 0, 0)

// ---------------- fused prep: cvt(x)->bf16 | W_attn^T | W_proj^T | cnt=0 ----------------

__global__ __launch_bounds__(256) void k_prep(const float* __restrict__ x, u16* __restrict__ xb,
                                              const float* __restrict__ W_attn, u16* __restrict__ Wat,
                                              const float* __restrict__ W_proj, u16* __restrict__ Wpt,
                                              unsigned* __restrict__ cnt) {
    const int b = blockIdx.x;
    const int tid = threadIdx.x;
    if (b == 0 && tid == 0) *cnt = 0u;  // flash job counter (re-zeroed every call)

    if (b < 2048) {  // cvt_x: 2048 blocks x 2048 elems
        const int i = (b * 256 + tid) * 8;
        float4 a = *(const float4*)(x + i);
        float4 c = *(const float4*)(x + i + 4);
        u16x8 o;
        o[0] = f2bf(a.x); o[1] = f2bf(a.y); o[2] = f2bf(a.z); o[3] = f2bf(a.w);
        o[4] = f2bf(c.x); o[5] = f2bf(c.y); o[6] = f2bf(c.z); o[7] = f2bf(c.w);
        *(u16x8*)(xb + i) = o;
        return;
    }
    const float* src;
    u16* dst;
    int bx, by, R, Cc;
    if (b < 5120) {
        const int t = b - 2048;          // 96 x 32 tiles
        bx = (t % 96) * 32; by = (t / 96) * 32;
        src = W_attn; dst = Wat; R = 1024; Cc = 3072;
    } else {
        const int t = b - 5120;          // 32 x 32 tiles
        bx = (t & 31) * 32; by = (t >> 5) * 32;
        src = W_proj; dst = Wpt; R = 1024; Cc = 1024;
    }
    __shared__ float tile[32][33];
    const int xi = tid & 31, yi = tid >> 5;  // 32 x 8
#pragma unroll
    for (int i = 0; i < 32; i += 8)
        tile[yi + i][xi] = src[(size_t)(by + yi + i) * Cc + bx + xi];
    __syncthreads();
#pragma unroll
    for (int i = 0; i < 32; i += 8)
        dst[(size_t)(bx + yi + i) * R + by + xi] = f2bf(tile[xi][yi + i]);
}

// ---------------- GEMM (flipped): C[f][t] = sum_k A[f][k]*Bt[t][k] + bias[f] --------
// 128(f) x 256(t) tile, BK=64, 8 waves as 2m x 4n (wave owns 64x64). 2-slot ring:
// prologue stages steps 0,1 (6 ops/wave each); loop: vmcnt(6) certifies step t ->
// s_barrier -> ds_read+MFMA(t) -> s_barrier -> stage t+2 (clamped dummy at tail)
// into the slot all waves just finished reading. Never vmcnt(0) in-loop.
// LDS chunk (rb, kh): 1KB written linearly by gld_lds (lane l -> row rb*16+(l&15),
// k = kh*32 + (l>>4)*8); frag read (g,c) = one b128 at g*128+c*8 (conflict-free;
// shared-k permutation k=8g..8g+7 on BOTH operands -> dot product invariant).
// C/D frag: lane(16g+c) reg r -> feature = fbase+r (contiguous), token = col c.

template <int EPI>
__global__ __launch_bounds__(512) void k_gemm(const u16* __restrict__ A, const u16* __restrict__ Bt,
                                              const float* __restrict__ bias,
                                              u16* __restrict__ outQ, u16* __restrict__ outK,
                                              u16* __restrict__ outVt, float* __restrict__ outF,
                                              int kd, int nbx) {
    __shared__ u16 Asm[2][8192];   // [slot][8 rb x (2 kh x 512)]  = 32KB
    __shared__ u16 Bsm[2][16384];  // [slot][16 rb x (2 kh x 512)] = 64KB
    const int tid = threadIdx.x;
    const int lane = tid & 63;
    const int wid = tid >> 6;        // 0..7
    const int wm = wid >> 2;         // 0..1 (feature)
    const int wn = wid & 3;          // 0..3 (token)
    const int c = lane & 15, g = lane >> 4;
    const int nwg = gridDim.x;
    const int swzb = ((int)blockIdx.x & 7) * (nwg >> 3) + ((int)blockIdx.x >> 3);
    const int m0 = (swzb % nbx) * 128;  // feature tile
    const int n0 = (swzb / nbx) * 256;  // token tile
    const int srow = lane & 15;         // staging: row within 16-row block
    const int scol = (lane >> 4) * 8;   // staging: k offset within 32-k half (u16)

    f32x4 acc[4][4] = {};
    const int nk = kd >> 6;  // BK=64

    auto stage = [&](int s, int sl) {
        const int k0 = s * 64;
#pragma unroll
        for (int kh = 0; kh < 2; ++kh)
            gld_lds16(A + (size_t)(m0 + wid * 16 + srow) * kd + k0 + kh * 32 + scol,
                      &Asm[sl][wid * 1024 + kh * 512]);
#pragma unroll
        for (int i = 0; i < 2; ++i) {
            const int rb = wid + i * 8;
#pragma unroll
            for (int kh = 0; kh < 2; ++kh)
                gld_lds16(Bt + (size_t)(n0 + rb * 16 + srow) * kd + k0 + kh * 32 + scol,
                          &Bsm[sl][rb * 1024 + kh * 512]);
        }
    };

    // prologue: depth-2 prefetch (12 vmem ops/wave)
    stage(0, 0);
    stage(1, 1);

    for (int t = 0; t < nk; ++t) {
        // my step-t ops are my 6 oldest outstanding: wait to <=6, then publish.
        asm volatile("s_waitcnt vmcnt(6)" ::: "memory");
        __builtin_amdgcn_s_barrier();
        __builtin_amdgcn_sched_barrier(0);

        const u16* Asl = Asm[t & 1];
        const u16* Bsl = Bsm[t & 1];
        bf16x8 af[4][2], bfm[4][2];
#pragma unroll
        for (int mi = 0; mi < 4; ++mi) {
            const u16* p = Asl + (wm * 4 + mi) * 1024 + g * 128 + c * 8;
            af[mi][0] = ldc(p);
            af[mi][1] = ldc(p + 512);
        }
#pragma unroll
        for (int ni = 0; ni < 4; ++ni) {
            const u16* p = Bsl + (wn * 4 + ni) * 1024 + g * 128 + c * 8;
            bfm[ni][0] = ldc(p);
            bfm[ni][1] = ldc(p + 512);
        }
        __builtin_amdgcn_s_setprio(1);
#pragma unroll
        for (int mi = 0; mi < 4; ++mi)
#pragma unroll
            for (int ni = 0; ni < 4; ++ni) {
                acc[mi][ni] = MFMA16(af[mi][0], bfm[ni][0], acc[mi][ni]);
                acc[mi][ni] = MFMA16(af[mi][1], bfm[ni][1], acc[mi][ni]);
            }
        __builtin_amdgcn_s_setprio(0);
        __builtin_amdgcn_sched_barrier(0);
        __builtin_amdgcn_s_barrier();   // all waves done reading slot t&1
        __builtin_amdgcn_sched_barrier(0);
        stage(t + 2 < nk ? t + 2 : nk - 1, t & 1);  // refill freed slot (dummy at tail)
    }
    asm volatile("s_waitcnt vmcnt(0)" ::: "memory");  // drain tail dummies

    const int mbase = m0 + wm * 64;  // features
    const int nbase = n0 + wn * 64;  // tokens
    if (EPI == 0) {
        const int part = m0 >> 10;  // 0=Q 1=K 2=V, uniform per block
#pragma unroll
        for (int mi = 0; mi < 4; ++mi) {
            const int fbase = mbase + mi * 16 + 4 * g;   // 4 contiguous features (r)
            const f32x4 bv = *(const f32x4*)(bias + fbase);
            const int fr = fbase & 1023;
            const int h = fr >> 6, d0 = fr & 63;
#pragma unroll
            for (int ni = 0; ni < 4; ++ni) {
                const int tok = nbase + ni * 16 + c;
                if (part == 2) {
#pragma unroll
                    for (int r = 0; r < 4; ++r)
                        outVt[(size_t)(fr + r) * T_SEQ + tok] = f2bf(acc[mi][ni][r] + bv[r]);
                } else {
                    u16x4 pk;
#pragma unroll
                    for (int r = 0; r < 4; ++r) {
                        float v = acc[mi][ni][r] + bv[r];
                        pk[r] = f2bf(part == 0 ? v * QSC : v);
                    }
                    u16* dst = (part == 0 ? outQ : outK);
                    *(u16x4*)(dst + (size_t)(h * T_SEQ + tok) * HD + d0) = pk;
                }
            }
        }
    } else {
#pragma unroll
        for (int mi = 0; mi < 4; ++mi) {
            const int fbase = mbase + mi * 16 + 4 * g;
            const f32x4 bv = *(const f32x4*)(bias + fbase);
#pragma unroll
            for (int ni = 0; ni < 4; ++ni) {
                const int tok = nbase + ni * 16 + c;
                f32x4 w;
#pragma unroll
                for (int r = 0; r < 4; ++r) w[r] = acc[mi][ni][r] + bv[r];
                *(f32x4*)(outF + (size_t)tok * C_DIM + fbase) = w;
            }
        }
    }
}

// ---------------- flash attention: split-kv, 8 waves x 256q, counted-vmcnt ring ----
// (R16 verified: 3-slot ring 48KB, depth-2, vmcnt(2)/tile, (512,4) = 64 VGPR.)

static __device__ __forceinline__ void p_gen(f32x4 s[4], int qabs, int kv0, int g,
                                             bool domask, bf16x8 pa[2]) {
    if (domask) {
#pragma unroll
        for (int tau = 0; tau < 4; ++tau) {
            const int kb = kv0 + 32 * (tau >> 1) + 4 * (tau & 1) + 8 * g;
#pragma unroll
            for (int r = 0; r < 4; ++r)
                if (kb + r > qabs) s[tau][r] = -3e38f;
        }
    }
    u16 pb[4][4];
#pragma unroll
    for (int tau = 0; tau < 4; ++tau)
#pragma unroll
        for (int r = 0; r < 4; ++r)
            pb[tau][r] = f2bf(__builtin_amdgcn_exp2f(s[tau][r]));  // exp2(-3e38)=0
    const u16x8 p0 = {pb[0][0], pb[0][1], pb[0][2], pb[0][3], pb[1][0], pb[1][1], pb[1][2], pb[1][3]};
    const u16x8 p1 = {pb[2][0], pb[2][1], pb[2][2], pb[2][3], pb[3][0], pb[3][1], pb[3][2], pb[3][3]};
    pa[0] = __builtin_bit_cast(bf16x8, p0);
    pa[1] = __builtin_bit_cast(bf16x8, p1);
}

__global__ __launch_bounds__(512, 4) void k_flash(const u16* __restrict__ Qg, const u16* __restrict__ Kg,
                                                  const u16* __restrict__ Vtg, u16* __restrict__ Ab,
                                                  u16* __restrict__ part, float* __restrict__ lpart,
                                                  unsigned* __restrict__ cnt) {
    __shared__ u16 sm[3][2][4096];  // 3-slot ring [slot][K/V][64*64], swizzled; 48KB
    __shared__ unsigned jslot;

    const int tid = threadIdx.x;
    const int lane = tid & 63;
    const int wid = tid >> 6;  // 0..7
    const int c = lane & 15, g = lane >> 4;
    const int srow = lane >> 3;
    const int sxu = (((lane & 7) * 16) ^ (srow << 4)) >> 1;

    const u16x8 onespat = {0x3F80, 0x3F80, 0x3F80, 0x3F80, 0x3F80, 0x3F80, 0x3F80, 0x3F80};
    const bf16x8 onesf = __builtin_bit_cast(bf16x8, onespat);

    for (;;) {
        if (tid == 0) jslot = atomicAdd(cnt, 1u);
        __syncthreads();
        const unsigned j = jslot;
        if (j >= (unsigned)NJOBS) break;

        const int head = (int)(j & 15u);
        const int idx = (int)(j >> 4);  // 0..71, ascending = longest chunks first
        int qb, ch, nc;
        if (idx < 16)      { qb = 15 - (idx >> 3); ch = idx & 7; nc = 8; }
        else if (idx < 30) { const int t = idx - 16; qb = 13 - t / 7;    ch = t % 7; nc = 7; }
        else if (idx < 42) { const int t = idx - 30; qb = 11 - t / 6;    ch = t % 6; nc = 6; }
        else if (idx < 52) { const int t = idx - 42; qb = 9 - t / 5;     ch = t % 5; nc = 5; }
        else if (idx < 60) { const int t = idx - 52; qb = 7 - (t >> 2);  ch = t & 3; nc = 4; }
        else if (idx < 66) { const int t = idx - 60; qb = 5 - t / 3;     ch = t % 3; nc = 3; }
        else if (idx < 70) { const int t = idx - 66; qb = 3 - (t >> 1);  ch = t & 1; nc = 2; }
        else               { qb = 1 - (idx - 70); ch = 0; nc = 1; }
        const int ntile = 4 * qb + 4;
        const int cbase = ntile / nc, crem = ntile % nc;
        const int len = cbase + (ch < crem ? 1 : 0);
        const int start = ch * cbase + (ch < crem ? ch : crem);

        const int q0w = qb * 256 + wid * 32;

        const u16* Qh = Qg + (size_t)head * (T_SEQ * HD);
        const u16* Kh = Kg + (size_t)head * (T_SEQ * HD);
        const u16* Vh = Vtg + (size_t)head * (HD * T_SEQ);

        bf16x8 qf[2][2];
#pragma unroll
        for (int h = 0; h < 2; ++h)
#pragma unroll
            for (int dc = 0; dc < 2; ++dc)
                qf[h][dc] = __builtin_bit_cast(
                    bf16x8, *(const u16x8*)(Qh + (q0w + 16 * h + c) * HD + dc * 32 + 8 * g));

        f32x4 o0[4] = {}, o1[4] = {}, ol0 = {}, ol1 = {};

        // prologue: stage tiles 0..1 (clamped) into slots 0..1 -> 4 vmem ops/wave
#pragma unroll
        for (int i = 0; i < 2; ++i) {
            const int ts = (i < len ? start + i : start + len - 1) * 64;
            gld_lds16(Kh + (ts + wid * 8 + srow) * HD + sxu, &sm[i][0][wid * 512]);
            gld_lds16(Vh + (wid * 8 + srow) * T_SEQ + ts + sxu, &sm[i][1][wid * 512]);
        }

        int cur = 0;  // slot holding tile t
        for (int t = 0; t < len; ++t) {
            asm volatile("s_waitcnt vmcnt(2)" ::: "memory");
            __builtin_amdgcn_s_barrier();
            __builtin_amdgcn_sched_barrier(0);
            {   // stage tile t+2 (clamped dummy past end) into slot (cur+2)%3
                const int ts = (t + 2 < len ? start + t + 2 : start + len - 1) * 64;
                const int sl = (cur == 0) ? 2 : cur - 1;  // (cur+2)%3
                gld_lds16(Kh + (ts + wid * 8 + srow) * HD + sxu, &sm[sl][0][wid * 512]);
                gld_lds16(Vh + (wid * 8 + srow) * T_SEQ + ts + sxu, &sm[sl][1][wid * 512]);
            }
            const int kv0 = (start + t) * 64;
            if (kv0 <= q0w + 31) {  // wave-uniform causal skip (barrier is outside)
                const u16* Kl = &sm[cur][0][0];
                const u16* Vl = &sm[cur][1][0];
                f32x4 s0[4], s1[4];
                __builtin_amdgcn_s_setprio(1);
#pragma unroll
                for (int tau = 0; tau < 4; ++tau) {
                    const int prow = 32 * (tau >> 1) + 4 * (tau & 1) + 8 * (c >> 2) + (c & 3);
                    const int sw = (prow & 7) << 4;
                    const u16* kb = Kl + prow * 64;
                    const bf16x8 k0 = ldfr(kb, (16 * g) ^ sw);
                    const bf16x8 k1 = ldfr(kb, (64 + 16 * g) ^ sw);
                    f32x4 z0 = {}, z1 = {};
                    z0 = MFMA16(k0, qf[0][0], z0);
                    s0[tau] = MFMA16(k1, qf[0][1], z0);
                    z1 = MFMA16(k0, qf[1][0], z1);
                    s1[tau] = MFMA16(k1, qf[1][1], z1);
                }
                __builtin_amdgcn_s_setprio(0);
                const bool dm0 = (kv0 + 63) > (q0w);
                const bool dm1 = (kv0 + 63) > (q0w + 16);
                bf16x8 pa0[2], pa1[2];
                p_gen(s0, q0w + c, kv0, g, dm0, pa0);
                p_gen(s1, q0w + 16 + c, kv0, g, dm1, pa1);
                const int swv = (c & 7) << 4;
                __builtin_amdgcn_s_setprio(1);
#pragma unroll
                for (int n = 0; n < 4; ++n) {
                    const u16* vb = Vl + (n * 16 + c) * 64;
                    const bf16x8 v0 = ldfr(vb, (16 * g) ^ swv);
                    const bf16x8 v1 = ldfr(vb, (64 + 16 * g) ^ swv);
                    o0[n] = MFMA16(v0, pa0[0], o0[n]);
                    o0[n] = MFMA16(v1, pa0[1], o0[n]);
                    o1[n] = MFMA16(v0, pa1[0], o1[n]);
                    o1[n] = MFMA16(v1, pa1[1], o1[n]);
                }
                ol0 = MFMA16(onesf, pa0[0], ol0);
                ol0 = MFMA16(onesf, pa0[1], ol0);
                ol1 = MFMA16(onesf, pa1[0], ol1);
                ol1 = MFMA16(onesf, pa1[1], ol1);
                __builtin_amdgcn_s_setprio(0);
            }
            cur = (cur == 2) ? 0 : cur + 1;
        }

        const int ql0 = wid * 32 + c;
        if (nc == 1) {
            const float li0 = 1.0f / ol0[0], li1 = 1.0f / ol1[0];
            u16* dst0 = Ab + (size_t)(qb * 256 + ql0) * C_DIM + head * HD;
            u16* dst1 = dst0 + (size_t)16 * C_DIM;
#pragma unroll
            for (int n = 0; n < 4; ++n) {
                u16x4 w0, w1;
#pragma unroll
                for (int r = 0; r < 4; ++r) {
                    w0[r] = f2bf(o0[n][r] * li0);
                    w1[r] = f2bf(o1[n][r] * li1);
                }
                *(u16x4*)(dst0 + n * 16 + 4 * g) = w0;
                *(u16x4*)(dst1 + n * 16 + 4 * g) = w1;
            }
        } else {
            u16* slot = part + (size_t)j * 16384u;
            float* lsl = lpart + (size_t)j * 256u;
#pragma unroll
            for (int n = 0; n < 4; ++n) {
                u16x4 w0, w1;
#pragma unroll
                for (int r = 0; r < 4; ++r) {
                    w0[r] = f2bf(o0[n][r]);
                    w1[r] = f2bf(o1[n][r]);
                }
                *(u16x4*)(slot + ql0 * 64 + n * 16 + 4 * g) = w0;
                *(u16x4*)(slot + (ql0 + 16) * 64 + n * 16 + 4 * g) = w1;
            }
            if (g == 0) {
                lsl[ql0] = ol0[0];
                lsl[ql0 + 16] = ol1[0];
            }
        }
        __syncthreads();  // drains vmcnt(0); ring + jslot safe for next job
    }
}

// ---------------- combine (qb >= 2 only; nc==1 jobs wrote Ab directly) ----------------

__global__ __launch_bounds__(512) void k_combine(const u16* __restrict__ part,
                                                 const float* __restrict__ lpart,
                                                 u16* __restrict__ Ab) {
    const int head = blockIdx.x / 14;
    const int qb = 2 + (blockIdx.x % 14);
    int nc, idx0;
    if (qb >= 14)      { nc = 8; idx0 = (15 - qb) * 8; }
    else if (qb >= 12) { nc = 7; idx0 = 16 + (13 - qb) * 7; }
    else if (qb >= 10) { nc = 6; idx0 = 30 + (11 - qb) * 6; }
    else if (qb >= 8)  { nc = 5; idx0 = 42 + (9 - qb) * 5; }
    else if (qb >= 6)  { nc = 4; idx0 = 52 + (7 - qb) * 4; }
    else if (qb >= 4)  { nc = 3; idx0 = 60 + (5 - qb) * 3; }
    else               { nc = 2; idx0 = 66 + (3 - qb) * 2; }

    const int q = threadIdx.x >> 1;        // 0..255
    const int dh = (threadIdx.x & 1) * 32; // 32-d half
    float acc[32] = {};
    float l = 0.f;
    for (int i = 0; i < nc; ++i) {
        const unsigned jj = (unsigned)(((idx0 + i) << 4) | head);
        const u16* sp = part + (size_t)jj * 16384u + q * 64 + dh;
#pragma unroll
        for (int v = 0; v < 4; ++v) {
            const u16x8 w = *(const u16x8*)(sp + 8 * v);
#pragma unroll
            for (int e = 0; e < 8; ++e) acc[8 * v + e] += bf2f(w[e]);
        }
        l += lpart[(size_t)jj * 256u + q];
    }
    const float li = 1.0f / l;
    u16* dst = Ab + (size_t)(qb * 256 + q) * C_DIM + head * HD + dh;
#pragma unroll
    for (int v = 0; v < 4; ++v) {
        u16x8 w;
#pragma unroll
        for (int e = 0; e < 8; ++e) w[e] = f2bf(acc[8 * v + e] * li);
        *(u16x8*)(dst + 8 * v) = w;
    }
}

// ---------------- launch ----------------

extern "C" void kernel_launch(void* const* d_in, const int* in_sizes, int n_in,
                              void* d_out, int out_size, void* d_ws, size_t ws_size,
                              hipStream_t stream) {
    const float* x      = (const float*)d_in[0];
    const float* W_attn = (const float*)d_in[1];
    const float* b_attn = (const float*)d_in[2];
    const float* W_proj = (const float*)d_in[3];
    const float* b_proj = (const float*)d_in[4];
    float* out = (float*)d_out;

    char* ws = (char*)d_ws;
    u16* xb    = (u16*)(ws);                 // 8 MB  x bf16; REUSED as Ab after flash
    u16* Wat   = (u16*)(ws + (8u << 20));    // 6 MB  W_attn^T bf16 [3072][1024]
    u16* Wpt   = (u16*)(ws + (14u << 20));   // 2 MB  W_proj^T bf16 [1024][1024]
    u16* Qb    = (u16*)(ws + (16u << 20));   // 8 MB  Q (pre-scaled) [16][4096][64]
    u16* Kb    = (u16*)(ws + (24u << 20));   // 8 MB  K [16][4096][64]
    u16* Vtb   = (u16*)(ws + (32u << 20));   // 8 MB  V^T [16][64][4096]
    u16* prt   = (u16*)(ws + (40u << 20));   // 36 MB O^T partials [1152][256][64] bf16
    float* lpt = (float*)(ws + (78u << 20)); // 1.2 MB l partials [1152][256] f32
    u16* Ab    = xb;                         // attention output overwrites dead xb

    unsigned* cnt = (unsigned*)d_out;  // zeroed by k_prep; proj GEMM overwrites all of d_out

    k_prep<<<6144, 256, 0, stream>>>(x, xb, W_attn, Wat, W_proj, Wpt, cnt);
    // flipped: A = weights (features), Bt = activations (tokens); 128f x 256t tiles
    k_gemm<0><<<384, 512, 0, stream>>>(Wat, xb, b_attn, Qb, Kb, Vtb, nullptr, 1024, 24);
    k_flash<<<768, 512, 0, stream>>>(Qb, Kb, Vtb, Ab, prt, lpt, cnt);
    k_combine<<<224, 512, 0, stream>>>(prt, lpt, Ab);
    k_gemm<1><<<128, 512, 0, stream>>>(Wpt, Ab, b_proj, nullptr, nullptr, nullptr, out, 1024, 8);
}

// Round 19
// 142.012 us; speedup vs baseline: 1.4415x; 1.4415x over previous
//
#include <hip/hip_runtime.h>
#include <hip/hip_bf16.h>

// GPT-2 attention block, MI355X. B=1 T=4096 C=1024 H=16 D=64.
// R18: revert GEMM to R16-verified structure (R17's 96KB ring = 1 block/CU,
//      2-round makespan, MfmaUtil 11.6% — 4th failed restructure; the 128²/BK64/
//      4-wave/3-per-CU loop stays). ONE change: gemm<1> retiled 128f x 64t via
//      template BN (512 blocks = 2/CU, was 256 = 1/CU = 1 wave/SIMD zero-TLP).
//      BN=128 instantiation is bit-identical to R16 gemm<0>. Flash = R16 3-slot
//      ring (63.7us verified), prep/combine verbatim.

typedef unsigned short u16;
typedef u16 u16x4 __attribute__((ext_vector_type(4)));
typedef u16 u16x8 __attribute__((ext_vector_type(8)));
typedef __bf16 bf16x8 __attribute__((ext_vector_type(8)));
typedef float f32x4 __attribute__((ext_vector_type(4)));

#define T_SEQ 4096
#define C_DIM 1024
#define NH 16
#define HD 64
#define QSC 0.18033688f  // 0.125 * log2(e): folded into Q at QKV epilogue
#define NJOBS 1152       // 16 heads x 72 chunk-jobs (256q rows, <=8 kv-tiles each)

static __device__ __forceinline__ u16 f2bf(float f) {
    __hip_bfloat16 h = __float2bfloat16(f);
    return __builtin_bit_cast(u16, h);
}

static __device__ __forceinline__ float bf2f(u16 u) {
    return __builtin_bit_cast(float, (unsigned)u << 16);
}

static __device__ __forceinline__ bf16x8 ldfr(const u16* base, int byteoff) {
    return __builtin_bit_cast(bf16x8, *(const u16x8*)(base + (byteoff >> 1)));
}

static __device__ __forceinline__ void gld_lds16(const void* g, void* l) {
    __builtin_amdgcn_global_load_lds((const __attribute__((address_space(1))) void*)g,
                                     (__attribute__((address_space(3))) void*)l, 16, 0, 0);
}

#define MFMA16(a, b, c) __builtin_amdgcn_mfma_f32_16x16x32_bf16((a), (b), (c), 0, 0, 0)

// ---------------- fused prep: cvt(x)->bf16 | W_attn^T | W_proj^T | cnt=0 ----------------

__global__ __launch_bounds__(256) void k_prep(const float* __restrict__ x, u16* __restrict__ xb,
                                              const float* __restrict__ W_attn, u16* __restrict__ Wat,
                                              const float* __restrict__ W_proj, u16* __restrict__ Wpt,
                                              unsigned* __restrict__ cnt) {
    const int b = blockIdx.x;
    const int tid = threadIdx.x;
    if (b == 0 && tid == 0) *cnt = 0u;  // flash job counter (re-zeroed every call)

    if (b < 2048) {  // cvt_x: 2048 blocks x 2048 elems
        const int i = (b * 256 + tid) * 8;
        float4 a = *(const float4*)(x + i);
        float4 c = *(const float4*)(x + i + 4);
        u16x8 o;
        o[0] = f2bf(a.x); o[1] = f2bf(a.y); o[2] = f2bf(a.z); o[3] = f2bf(a.w);
        o[4] = f2bf(c.x); o[5] = f2bf(c.y); o[6] = f2bf(c.z); o[7] = f2bf(c.w);
        *(u16x8*)(xb + i) = o;
        return;
    }
    const float* src;
    u16* dst;
    int bx, by, R, Cc;
    if (b < 5120) {
        const int t = b - 2048;          // 96 x 32 tiles
        bx = (t % 96) * 32; by = (t / 96) * 32;
        src = W_attn; dst = Wat; R = 1024; Cc = 3072;
    } else {
        const int t = b - 5120;          // 32 x 32 tiles
        bx = (t & 31) * 32; by = (t >> 5) * 32;
        src = W_proj; dst = Wpt; R = 1024; Cc = 1024;
    }
    __shared__ float tile[32][33];
    const int xi = tid & 31, yi = tid >> 5;  // 32 x 8
#pragma unroll
    for (int i = 0; i < 32; i += 8)
        tile[yi + i][xi] = src[(size_t)(by + yi + i) * Cc + bx + xi];
    __syncthreads();
#pragma unroll
    for (int i = 0; i < 32; i += 8)
        dst[(size_t)(bx + yi + i) * R + by + xi] = f2bf(tile[xi][yi + i]);
}

// ---------------- GEMM (flipped): C[f][t] = sum_k A[f][k]*Bt[t][k] + bias[f] --------
// R16-verified loop: 128f x BN(t) tile, BK=64, 4 waves (2x2; wave = 64f x BN/2 t),
// gload_lds + pre-swizzled source, b128 fragment reads, single-buffer K-loop
// (latency hidden by multi-block TLP: BN=128 -> 3 blocks/CU, BN=64 -> 2+ blocks/CU).
// C/D frag: lane(16g+c) reg r -> feature = fbase+r (contiguous), token = col c.

template <int EPI, int BN>
__global__ __launch_bounds__(256) void k_gemm(const u16* __restrict__ A, const u16* __restrict__ Bt,
                                              const float* __restrict__ bias,
                                              u16* __restrict__ outQ, u16* __restrict__ outK,
                                              u16* __restrict__ outVt, float* __restrict__ outF,
                                              int kd, int nbx) {
    constexpr int NI = BN / 32;  // per-wave ni count (wave token span = BN/2)
    __shared__ u16 Al[128 * 64];
    __shared__ u16 Bl[BN * 64];
    const int tid = threadIdx.x;
    const int lane = tid & 63;
    const int wid = tid >> 6;
    const int wm = wid >> 1, wn = wid & 1;
    const int c = lane & 15, g = lane >> 4;
    const int nwg = gridDim.x;
    const int swzb = ((int)blockIdx.x & 7) * (nwg >> 3) + ((int)blockIdx.x >> 3);
    const int m0 = (swzb % nbx) * 128;  // feature tile
    const int n0 = (swzb / nbx) * BN;   // token tile
    const int srow = lane >> 3;
    const int sxu = (((lane & 7) * 16) ^ (srow << 4)) >> 1;
    const int swa = (c & 7) << 4;

    f32x4 acc[4][NI] = {};

    for (int k0 = 0; k0 < kd; k0 += 64) {
#pragma unroll
        for (int i = 0; i < 4; ++i) {  // A: 16 chunks of 8 rows
            const int ch = wid * 4 + i;
            const int row = ch * 8 + srow;
            gld_lds16(A + (size_t)(m0 + row) * kd + k0 + sxu, &Al[ch * 512]);
        }
#pragma unroll
        for (int i = 0; i < NI; ++i) {  // B: BN/8 chunks of 8 rows
            const int ch = wid * NI + i;
            const int row = ch * 8 + srow;
            gld_lds16(Bt + (size_t)(n0 + row) * kd + k0 + sxu, &Bl[ch * 512]);
        }
        __syncthreads();
        bf16x8 af[4][2], bfm[NI][2];
#pragma unroll
        for (int mi = 0; mi < 4; ++mi) {
            const u16* p = Al + (wm * 64 + mi * 16 + c) * 64;
            af[mi][0] = ldfr(p, (16 * g) ^ swa);
            af[mi][1] = ldfr(p, (64 + 16 * g) ^ swa);
        }
#pragma unroll
        for (int ni = 0; ni < NI; ++ni) {
            const u16* p = Bl + (wn * (BN / 2) + ni * 16 + c) * 64;
            bfm[ni][0] = ldfr(p, (16 * g) ^ swa);
            bfm[ni][1] = ldfr(p, (64 + 16 * g) ^ swa);
        }
#pragma unroll
        for (int mi = 0; mi < 4; ++mi)
#pragma unroll
            for (int ni = 0; ni < NI; ++ni) {
                acc[mi][ni] = MFMA16(af[mi][0], bfm[ni][0], acc[mi][ni]);
                acc[mi][ni] = MFMA16(af[mi][1], bfm[ni][1], acc[mi][ni]);
            }
        __syncthreads();
    }

    const int mbase = m0 + wm * 64;            // features
    const int nbase = n0 + wn * (BN / 2);      // tokens
    if (EPI == 0) {
        const int part = m0 >> 10;  // 0=Q 1=K 2=V, uniform per block
#pragma unroll
        for (int mi = 0; mi < 4; ++mi) {
            const int fbase = mbase + mi * 16 + 4 * g;   // 4 contiguous features (r)
            const f32x4 bv = *(const f32x4*)(bias + fbase);
            const int fr = fbase & 1023;
            const int h = fr >> 6, d0 = fr & 63;
#pragma unroll
            for (int ni = 0; ni < NI; ++ni) {
                const int tok = nbase + ni * 16 + c;
                if (part == 2) {
#pragma unroll
                    for (int r = 0; r < 4; ++r)
                        outVt[(size_t)(fr + r) * T_SEQ + tok] = f2bf(acc[mi][ni][r] + bv[r]);
                } else {
                    u16x4 pk;
#pragma unroll
                    for (int r = 0; r < 4; ++r) {
                        float v = acc[mi][ni][r] + bv[r];
                        pk[r] = f2bf(part == 0 ? v * QSC : v);
                    }
                    u16* dst = (part == 0 ? outQ : outK);
                    *(u16x4*)(dst + (size_t)(h * T_SEQ + tok) * HD + d0) = pk;
                }
            }
        }
    } else {
#pragma unroll
        for (int mi = 0; mi < 4; ++mi) {
            const int fbase = mbase + mi * 16 + 4 * g;
            const f32x4 bv = *(const f32x4*)(bias + fbase);
#pragma unroll
            for (int ni = 0; ni < NI; ++ni) {
                const int tok = nbase + ni * 16 + c;
                f32x4 w;
#pragma unroll
                for (int r = 0; r < 4; ++r) w[r] = acc[mi][ni][r] + bv[r];
                *(f32x4*)(outF + (size_t)tok * C_DIM + fbase) = w;
            }
        }
    }
}

// ---------------- flash attention: split-kv, 8 waves x 256q, counted-vmcnt ring ----
// (R16 verified: 3-slot ring 48KB, depth-2, vmcnt(2)/tile, (512,4) = 64 VGPR.)

static __device__ __forceinline__ void p_gen(f32x4 s[4], int qabs, int kv0, int g,
                                             bool domask, bf16x8 pa[2]) {
    if (domask) {
#pragma unroll
        for (int tau = 0; tau < 4; ++tau) {
            const int kb = kv0 + 32 * (tau >> 1) + 4 * (tau & 1) + 8 * g;
#pragma unroll
            for (int r = 0; r < 4; ++r)
                if (kb + r > qabs) s[tau][r] = -3e38f;
        }
    }
    u16 pb[4][4];
#pragma unroll
    for (int tau = 0; tau < 4; ++tau)
#pragma unroll
        for (int r = 0; r < 4; ++r)
            pb[tau][r] = f2bf(__builtin_amdgcn_exp2f(s[tau][r]));  // exp2(-3e38)=0
    const u16x8 p0 = {pb[0][0], pb[0][1], pb[0][2], pb[0][3], pb[1][0], pb[1][1], pb[1][2], pb[1][3]};
    const u16x8 p1 = {pb[2][0], pb[2][1], pb[2][2], pb[2][3], pb[3][0], pb[3][1], pb[3][2], pb[3][3]};
    pa[0] = __builtin_bit_cast(bf16x8, p0);
    pa[1] = __builtin_bit_cast(bf16x8, p1);
}

__global__ __launch_bounds__(512, 4) void k_flash(const u16* __restrict__ Qg, const u16* __restrict__ Kg,
                                                  const u16* __restrict__ Vtg, u16* __restrict__ Ab,
                                                  u16* __restrict__ part, float* __restrict__ lpart,
                                                  unsigned* __restrict__ cnt) {
    __shared__ u16 sm[3][2][4096];  // 3-slot ring [slot][K/V][64*64], swizzled; 48KB
    __shared__ unsigned jslot;

    const int tid = threadIdx.x;
    const int lane = tid & 63;
    const int wid = tid >> 6;  // 0..7
    const int c = lane & 15, g = lane >> 4;
    const int srow = lane >> 3;
    const int sxu = (((lane & 7) * 16) ^ (srow << 4)) >> 1;

    const u16x8 onespat = {0x3F80, 0x3F80, 0x3F80, 0x3F80, 0x3F80, 0x3F80, 0x3F80, 0x3F80};
    const bf16x8 onesf = __builtin_bit_cast(bf16x8, onespat);

    for (;;) {
        if (tid == 0) jslot = atomicAdd(cnt, 1u);
        __syncthreads();
        const unsigned j = jslot;
        if (j >= (unsigned)NJOBS) break;

        const int head = (int)(j & 15u);
        const int idx = (int)(j >> 4);  // 0..71, ascending = longest chunks first
        int qb, ch, nc;
        if (idx < 16)      { qb = 15 - (idx >> 3); ch = idx & 7; nc = 8; }
        else if (idx < 30) { const int t = idx - 16; qb = 13 - t / 7;    ch = t % 7; nc = 7; }
        else if (idx < 42) { const int t = idx - 30; qb = 11 - t / 6;    ch = t % 6; nc = 6; }
        else if (idx < 52) { const int t = idx - 42; qb = 9 - t / 5;     ch = t % 5; nc = 5; }
        else if (idx < 60) { const int t = idx - 52; qb = 7 - (t >> 2);  ch = t & 3; nc = 4; }
        else if (idx < 66) { const int t = idx - 60; qb = 5 - t / 3;     ch = t % 3; nc = 3; }
        else if (idx < 70) { const int t = idx - 66; qb = 3 - (t >> 1);  ch = t & 1; nc = 2; }
        else               { qb = 1 - (idx - 70); ch = 0; nc = 1; }
        const int ntile = 4 * qb + 4;
        const int cbase = ntile / nc, crem = ntile % nc;
        const int len = cbase + (ch < crem ? 1 : 0);
        const int start = ch * cbase + (ch < crem ? ch : crem);

        const int q0w = qb * 256 + wid * 32;

        const u16* Qh = Qg + (size_t)head * (T_SEQ * HD);
        const u16* Kh = Kg + (size_t)head * (T_SEQ * HD);
        const u16* Vh = Vtg + (size_t)head * (HD * T_SEQ);

        bf16x8 qf[2][2];
#pragma unroll
        for (int h = 0; h < 2; ++h)
#pragma unroll
            for (int dc = 0; dc < 2; ++dc)
                qf[h][dc] = __builtin_bit_cast(
                    bf16x8, *(const u16x8*)(Qh + (q0w + 16 * h + c) * HD + dc * 32 + 8 * g));

        f32x4 o0[4] = {}, o1[4] = {}, ol0 = {}, ol1 = {};

        // prologue: stage tiles 0..1 (clamped) into slots 0..1 -> 4 vmem ops/wave
#pragma unroll
        for (int i = 0; i < 2; ++i) {
            const int ts = (i < len ? start + i : start + len - 1) * 64;
            gld_lds16(Kh + (ts + wid * 8 + srow) * HD + sxu, &sm[i][0][wid * 512]);
            gld_lds16(Vh + (wid * 8 + srow) * T_SEQ + ts + sxu, &sm[i][1][wid * 512]);
        }

        int cur = 0;  // slot holding tile t
        for (int t = 0; t < len; ++t) {
            asm volatile("s_waitcnt vmcnt(2)" ::: "memory");
            __builtin_amdgcn_s_barrier();
            __builtin_amdgcn_sched_barrier(0);
            {   // stage tile t+2 (clamped dummy past end) into slot (cur+2)%3
                const int ts = (t + 2 < len ? start + t + 2 : start + len - 1) * 64;
                const int sl = (cur == 0) ? 2 : cur - 1;  // (cur+2)%3
                gld_lds16(Kh + (ts + wid * 8 + srow) * HD + sxu, &sm[sl][0][wid * 512]);
                gld_lds16(Vh + (wid * 8 + srow) * T_SEQ + ts + sxu, &sm[sl][1][wid * 512]);
            }
            const int kv0 = (start + t) * 64;
            if (kv0 <= q0w + 31) {  // wave-uniform causal skip (barrier is outside)
                const u16* Kl = &sm[cur][0][0];
                const u16* Vl = &sm[cur][1][0];
                f32x4 s0[4], s1[4];
                __builtin_amdgcn_s_setprio(1);
#pragma unroll
                for (int tau = 0; tau < 4; ++tau) {
                    const int prow = 32 * (tau >> 1) + 4 * (tau & 1) + 8 * (c >> 2) + (c & 3);
                    const int sw = (prow & 7) << 4;
                    const u16* kb = Kl + prow * 64;
                    const bf16x8 k0 = ldfr(kb, (16 * g) ^ sw);
                    const bf16x8 k1 = ldfr(kb, (64 + 16 * g) ^ sw);
                    f32x4 z0 = {}, z1 = {};
                    z0 = MFMA16(k0, qf[0][0], z0);
                    s0[tau] = MFMA16(k1, qf[0][1], z0);
                    z1 = MFMA16(k0, qf[1][0], z1);
                    s1[tau] = MFMA16(k1, qf[1][1], z1);
                }
                __builtin_amdgcn_s_setprio(0);
                const bool dm0 = (kv0 + 63) > (q0w);
                const bool dm1 = (kv0 + 63) > (q0w + 16);
                bf16x8 pa0[2], pa1[2];
                p_gen(s0, q0w + c, kv0, g, dm0, pa0);
                p_gen(s1, q0w + 16 + c, kv0, g, dm1, pa1);
                const int swv = (c & 7) << 4;
                __builtin_amdgcn_s_setprio(1);
#pragma unroll
                for (int n = 0; n < 4; ++n) {
                    const u16* vb = Vl + (n * 16 + c) * 64;
                    const bf16x8 v0 = ldfr(vb, (16 * g) ^ swv);
                    const bf16x8 v1 = ldfr(vb, (64 + 16 * g) ^ swv);
                    o0[n] = MFMA16(v0, pa0[0], o0[n]);
                    o0[n] = MFMA16(v1, pa0[1], o0[n]);
                    o1[n] = MFMA16(v0, pa1[0], o1[n]);
                    o1[n] = MFMA16(v1, pa1[1], o1[n]);
                }
                ol0 = MFMA16(onesf, pa0[0], ol0);
                ol0 = MFMA16(onesf, pa0[1], ol0);
                ol1 = MFMA16(onesf, pa1[0], ol1);
                ol1 = MFMA16(onesf, pa1[1], ol1);
                __builtin_amdgcn_s_setprio(0);
            }
            cur = (cur == 2) ? 0 : cur + 1;
        }

        const int ql0 = wid * 32 + c;
        if (nc == 1) {
            const float li0 = 1.0f / ol0[0], li1 = 1.0f / ol1[0];
            u16* dst0 = Ab + (size_t)(qb * 256 + ql0) * C_DIM + head * HD;
            u16* dst1 = dst0 + (size_t)16 * C_DIM;
#pragma unroll
            for (int n = 0; n < 4; ++n) {
                u16x4 w0, w1;
#pragma unroll
                for (int r = 0; r < 4; ++r) {
                    w0[r] = f2bf(o0[n][r] * li0);
                    w1[r] = f2bf(o1[n][r] * li1);
                }
                *(u16x4*)(dst0 + n * 16 + 4 * g) = w0;
                *(u16x4*)(dst1 + n * 16 + 4 * g) = w1;
            }
        } else {
            u16* slot = part + (size_t)j * 16384u;
            float* lsl = lpart + (size_t)j * 256u;
#pragma unroll
            for (int n = 0; n < 4; ++n) {
                u16x4 w0, w1;
#pragma unroll
                for (int r = 0; r < 4; ++r) {
                    w0[r] = f2bf(o0[n][r]);
                    w1[r] = f2bf(o1[n][r]);
                }
                *(u16x4*)(slot + ql0 * 64 + n * 16 + 4 * g) = w0;
                *(u16x4*)(slot + (ql0 + 16) * 64 + n * 16 + 4 * g) = w1;
            }
            if (g == 0) {
                lsl[ql0] = ol0[0];
                lsl[ql0 + 16] = ol1[0];
            }
        }
        __syncthreads();  // drains vmcnt(0); ring + jslot safe for next job
    }
}

// ---------------- combine (qb >= 2 only; nc==1 jobs wrote Ab directly) ----------------

__global__ __launch_bounds__(512) void k_combine(const u16* __restrict__ part,
                                                 const float* __restrict__ lpart,
                                                 u16* __restrict__ Ab) {
    const int head = blockIdx.x / 14;
    const int qb = 2 + (blockIdx.x % 14);
    int nc, idx0;
    if (qb >= 14)      { nc = 8; idx0 = (15 - qb) * 8; }
    else if (qb >= 12) { nc = 7; idx0 = 16 + (13 - qb) * 7; }
    else if (qb >= 10) { nc = 6; idx0 = 30 + (11 - qb) * 6; }
    else if (qb >= 8)  { nc = 5; idx0 = 42 + (9 - qb) * 5; }
    else if (qb >= 6)  { nc = 4; idx0 = 52 + (7 - qb) * 4; }
    else if (qb >= 4)  { nc = 3; idx0 = 60 + (5 - qb) * 3; }
    else               { nc = 2; idx0 = 66 + (3 - qb) * 2; }

    const int q = threadIdx.x >> 1;        // 0..255
    const int dh = (threadIdx.x & 1) * 32; // 32-d half
    float acc[32] = {};
    float l = 0.f;
    for (int i = 0; i < nc; ++i) {
        const unsigned jj = (unsigned)(((idx0 + i) << 4) | head);
        const u16* sp = part + (size_t)jj * 16384u + q * 64 + dh;
#pragma unroll
        for (int v = 0; v < 4; ++v) {
            const u16x8 w = *(const u16x8*)(sp + 8 * v);
#pragma unroll
            for (int e = 0; e < 8; ++e) acc[8 * v + e] += bf2f(w[e]);
        }
        l += lpart[(size_t)jj * 256u + q];
    }
    const float li = 1.0f / l;
    u16* dst = Ab + (size_t)(qb * 256 + q) * C_DIM + head * HD + dh;
#pragma unroll
    for (int v = 0; v < 4; ++v) {
        u16x8 w;
#pragma unroll
        for (int e = 0; e < 8; ++e) w[e] = f2bf(acc[8 * v + e] * li);
        *(u16x8*)(dst + 8 * v) = w;
    }
}

// ---------------- launch ----------------

extern "C" void kernel_launch(void* const* d_in, const int* in_sizes, int n_in,
                              void* d_out, int out_size, void* d_ws, size_t ws_size,
                              hipStream_t stream) {
    const float* x      = (const float*)d_in[0];
    const float* W_attn = (const float*)d_in[1];
    const float* b_attn = (const float*)d_in[2];
    const float* W_proj = (const float*)d_in[3];
    const float* b_proj = (const float*)d_in[4];
    float* out = (float*)d_out;

    char* ws = (char*)d_ws;
    u16* xb    = (u16*)(ws);                 // 8 MB  x bf16; REUSED as Ab after flash
    u16* Wat   = (u16*)(ws + (8u << 20));    // 6 MB  W_attn^T bf16 [3072][1024]
    u16* Wpt   = (u16*)(ws + (14u << 20));   // 2 MB  W_proj^T bf16 [1024][1024]
    u16* Qb    = (u16*)(ws + (16u << 20));   // 8 MB  Q (pre-scaled) [16][4096][64]
    u16* Kb    = (u16*)(ws + (24u << 20));   // 8 MB  K [16][4096][64]
    u16* Vtb   = (u16*)(ws + (32u << 20));   // 8 MB  V^T [16][64][4096]
    u16* prt   = (u16*)(ws + (40u << 20));   // 36 MB O^T partials [1152][256][64] bf16
    float* lpt = (float*)(ws + (78u << 20)); // 1.2 MB l partials [1152][256] f32
    u16* Ab    = xb;                         // attention output overwrites dead xb

    unsigned* cnt = (unsigned*)d_out;  // zeroed by k_prep; proj GEMM overwrites all of d_out

    k_prep<<<6144, 256, 0, stream>>>(x, xb, W_attn, Wat, W_proj, Wpt, cnt);
    // flipped: A = weights (features), Bt = activations (tokens)
    k_gemm<0, 128><<<768, 256, 0, stream>>>(Wat, xb, b_attn, Qb, Kb, Vtb, nullptr, 1024, 24);
    k_flash<<<768, 512, 0, stream>>>(Qb, Kb, Vtb, Ab, prt, lpt, cnt);
    k_combine<<<224, 512, 0, stream>>>(prt, lpt, Ab);
    k_gemm<1, 64><<<512, 256, 0, stream>>>(Wpt, Ab, b_proj, nullptr, nullptr, nullptr, out, 1024, 8);
}